// Round 18
// baseline (999.608 us; speedup 1.0000x reference)
//
#include <hip/hip_runtime.h>
#include <cmath>

#define B_ 256
#define T_ 20
#define H_ 512
#define V_ 8964
#define LQ_ 40
#define LH_ 80
#define LI_ 49
#define BT_ (B_ * T_)   // 5120
#define BH_ (B_ * H_)   // 131072
#define NPAD_ 9216      // V_ padded to multiple of 256 (for 256-wide dec2 tiles)
#define BETA_ 3.0f

// mega-kernel block ranges (LSTM + ctx-projection helpers only)
#define MEGA_LSTM_ 128
#define MEGA_CTXQ_ 320
#define MEGA_CTXH_ 640
#define MEGA_CTXI_ 392
#define MEGA_CTX_ (MEGA_CTXQ_ + MEGA_CTXH_ + MEGA_CTXI_)   // 1352
#define MEGA_GRID_ (MEGA_LSTM_ + MEGA_CTX_)                // 1480

// prep-kernel block ranges
#define PREP_WCVT_ 2560           // 8 weights, 5,242,880 elems
#define PREP_WD2_  9216           // NPAD*2048 / 2048
#define PREP_EMB_  1280
#define PREP_PERM_ 2048
#define PREP_H0_   128
#define PREP_BIAS_ 2
#define PREP_GRID_ (PREP_WCVT_ + PREP_WD2_ + PREP_EMB_ + PREP_PERM_ + PREP_H0_ + PREP_BIAS_)

typedef __attribute__((ext_vector_type(8))) short bf16x8;
typedef __attribute__((ext_vector_type(4))) float f32x4;
typedef __attribute__((ext_vector_type(8))) unsigned short u16x8;

static __device__ __forceinline__ unsigned short f2bf(float f) {
    union { float f; unsigned u; } v; v.f = f;
    unsigned r = v.u + 0x7FFF + ((v.u >> 16) & 1);
    return (unsigned short)(r >> 16);
}
static __device__ __forceinline__ float bf2f(unsigned short u) {
    union { unsigned u; float f; } v; v.u = ((unsigned)u) << 16;
    return v.f;
}
static __device__ __forceinline__ float fast_tanh(float x) {
    const float e = __expf(2.f * x);
    return 1.f - 2.f * __builtin_amdgcn_rcpf(e + 1.f);
}
static __device__ __forceinline__ float fast_sigmoid(float x) {
    return __builtin_amdgcn_rcpf(1.f + __expf(-x));
}
static __device__ __forceinline__ void st16_sc(unsigned short* p, unsigned short v) {
    unsigned int vv = v;
    asm volatile("global_store_short %0, %1, off sc0 sc1" :: "v"(p), "v"(vv) : "memory");
}
static __device__ __forceinline__ int ld32_sc(const int* p) {
    int v;
    asm volatile("global_load_dword %0, %1, off sc0 sc1\n\t"
                 "s_waitcnt vmcnt(0)"
                 : "=v"(v) : "v"(p) : "memory");
    return v;
}
#define GLD16(g, l) __builtin_amdgcn_global_load_lds(                                   \
    (const __attribute__((address_space(1))) unsigned int*)(unsigned long long)(const void*)(g), \
    (__attribute__((address_space(3))) unsigned int*)(unsigned int)(unsigned long long)(void*)(l), \
    16, 0, 0)

static __device__ __forceinline__ u16x8 cvt8(const float* p)
{
    float4 a = *reinterpret_cast<const float4*>(p);
    float4 b = *reinterpret_cast<const float4*>(p + 4);
    u16x8 v;
    v[0] = f2bf(a.x); v[1] = f2bf(a.y); v[2] = f2bf(a.z); v[3] = f2bf(a.w);
    v[4] = f2bf(b.x); v[5] = f2bf(b.y); v[6] = f2bf(b.z); v[7] = f2bf(b.w);
    return v;
}

// ---------------------------------------------------------------------------
// Consolidated prep kernel.
// ---------------------------------------------------------------------------
struct PrepArgs {
    const float* wsrc[8]; unsigned short* wdst[8];
    const float* Wd2; unsigned short* Wd2p;
    const float* emb; unsigned short* emb_bf;
    const float* psrc[4]; unsigned short* pdst[4];
    const float* h0; unsigned short* hbuf;
    const float* bih; const float* bhh; float* bp0; float* bp1;
};

__global__ __launch_bounds__(256) void prep_kernel(PrepArgs a)
{
    static constexpr long long WSZ[8] = {524288, 524288, 524288, 262144,
                                         262144, 262144, 786432, 2097152};
    int g = blockIdx.x;
    const int tid = threadIdx.x;

    if (g < PREP_WCVT_) {
        long long off = (long long)g * 2048;
        int seg = 0;
#pragma unroll
        for (int i = 0; i < 8; ++i)
            if (seg == i && off >= WSZ[i]) { off -= WSZ[i]; ++seg; }
        const long long e = off + (long long)tid * 8;
        *reinterpret_cast<u16x8*>(a.wdst[seg] + e) = cvt8(a.wsrc[seg] + e);
        return;
    }
    g -= PREP_WCVT_;
    if (g < PREP_WD2_) {
        const long long e = (long long)g * 2048 + tid * 8;
        const long long row = e >> 11;
        u16x8 v;
        if (row < V_) v = cvt8(a.Wd2 + e);
        else v = (u16x8)0;
        *reinterpret_cast<u16x8*>(a.Wd2p + e) = v;
        return;
    }
    g -= PREP_WD2_;
    if (g < PREP_EMB_) {
        const long long e = (long long)g * 2048 + tid * 8;
        *reinterpret_cast<u16x8*>(a.emb_bf + e) = cvt8(a.emb + e);
        return;
    }
    g -= PREP_EMB_;
    if (g < PREP_PERM_) {
        const int which = g >> 9;
        const long long e0 = ((long long)(g & 511) * 256 + tid) * 8;
        const int drow = (int)(e0 >> 9);
        const int col = (int)(e0 & 511);
        const int gg = (drow >> 4) & 3;
        const int hsrc = ((drow >> 6) << 4) | (drow & 15);
        const int srow = (gg << 9) | hsrc;
        *reinterpret_cast<u16x8*>(a.pdst[which] + e0) =
            cvt8(a.psrc[which] + (long long)srow * 512 + col);
        return;
    }
    g -= PREP_PERM_;
    if (g < PREP_H0_) {
        const int half = g >> 6;
        const long long e = (long long)(g & 63) * 2048 + tid * 8;
        unsigned short* dst = a.hbuf + (half ? 4LL * BH_ : 0LL);
        *reinterpret_cast<u16x8*>(dst + e) = cvt8(a.h0 + (long long)half * BH_ + e);
        return;
    }
    g -= PREP_H0_;
    {
        const float* b1 = g ? a.bih + 2048 : a.bih;
        const float* b2 = g ? a.bhh + 2048 : a.bhh;
        float* dst = g ? a.bp1 : a.bp0;
#pragma unroll
        for (int i = 0; i < 8; ++i) {
            const int n = i * 256 + tid;
            const int gg = (n >> 4) & 3;
            const int h = ((n >> 6) << 4) | (n & 15);
            const int orig = (gg << 9) | h;
            dst[n] = b1[orig] + b2[orig];
        }
    }
}

// ---------------------------------------------------------------------------
static __device__ __forceinline__ int4 ldA8f(const float* A, long long idx)
{
    union { int4 i4; u16x8 v; } r;
    r.v = cvt8(A + idx);
    return r.i4;
}

// ---------------------------------------------------------------------------
// bf16 MFMA GEMM (128x128, BK=32, double-buffered, one barrier/K-step).
// Used for proj3 / Wcat / dec1.
// ---------------------------------------------------------------------------
template <int ACT, int OUTBF, int AF32>
__global__ __launch_bounds__(256, 2) void mfma_gemm(
    const void* __restrict__ A, const unsigned short* __restrict__ W,
    const float* __restrict__ bias1, const float* __restrict__ bias2,
    void* __restrict__ C, long long ldc, int Nreal, int K)
{
    __shared__ __align__(16) unsigned short As[2][128][32];
    __shared__ __align__(16) unsigned short Bs[2][128][32];
    const int tid = threadIdx.x;
    const int lane = tid & 63;
    const int wave = tid >> 6;
    const int wm = wave >> 1, wn = wave & 1;

    const int nwg = gridDim.x * gridDim.y;
    const int orig = blockIdx.y * gridDim.x + blockIdx.x;
    const int xcd = orig & 7, base = orig >> 3;
    const int q8 = nwg >> 3, r8 = nwg & 7;
    const int wg = (xcd < r8 ? xcd * (q8 + 1) : r8 * (q8 + 1) + (xcd - r8) * q8) + base;

    int MI = 8192 / (K << AF32);
    if (MI < 1) MI = 1;
    if (MI > (int)gridDim.y) MI = gridDim.y;
    const int slabSz = gridDim.x * MI;
    const int fullSlabs = gridDim.y / MI;
    const int fullRegion = fullSlabs * slabSz;
    int m0, n0;
    if (wg < fullRegion) {
        const int mb = wg / slabSz, rem = wg % slabSz;
        m0 = (mb * MI + rem % MI) * 128;
        n0 = (rem / MI) * 128;
    } else {
        const int rem = wg - fullRegion;
        const int TM = gridDim.y - fullSlabs * MI;
        m0 = (fullSlabs * MI + rem % TM) * 128;
        n0 = (rem / TM) * 128;
    }

    const int r = tid >> 2;
    const int ck = (tid & 3) * 8;

    const unsigned short* Wp = W + (long long)n0 * K;

    f32x4 acc[4][4] = {};
    int cur = 0;

    if constexpr (!AF32) {
        const unsigned short* Ab = (const unsigned short*)A;
        auto issue = [&](int k0, int buf) {
            const unsigned short* ga0 = Ab + (long long)(m0 + r) * K + k0 + ck;
            const unsigned short* ga1 = Ab + (long long)(m0 + r + 64) * K + k0 + ck;
            const unsigned short* gb0 = Wp + (long long)r * K + k0 + ck;
            const unsigned short* gb1 = Wp + (long long)(r + 64) * K + k0 + ck;
            char* lA = (char*)&As[buf][0][0] + wave * 1024;
            char* lB = (char*)&Bs[buf][0][0] + wave * 1024;
            GLD16(ga0, lA);
            GLD16(ga1, lA + 4096);
            GLD16(gb0, lB);
            GLD16(gb1, lB + 4096);
        };
        issue(0, 0);
        for (int k0 = 0; k0 < K; k0 += 32, cur ^= 1) {
            __syncthreads();
            if (k0 + 32 < K) issue(k0 + 32, cur ^ 1);
            const int lr = lane & 15, lk = (lane >> 4) * 8;
            bf16x8 af[4], bfr[4];
#pragma unroll
            for (int i = 0; i < 4; ++i) {
                af[i]  = *reinterpret_cast<const bf16x8*>(&As[cur][wm * 64 + i * 16 + lr][lk]);
                bfr[i] = *reinterpret_cast<const bf16x8*>(&Bs[cur][wn * 64 + i * 16 + lr][lk]);
            }
#pragma unroll
            for (int i = 0; i < 4; ++i)
#pragma unroll
                for (int j = 0; j < 4; ++j)
                    acc[i][j] = __builtin_amdgcn_mfma_f32_16x16x32_bf16(
                        af[i], bfr[j], acc[i][j], 0, 0, 0);
        }
    } else {
        const float* Af = (const float*)A;
        int4 ra0, ra1, rb0, rb1;
        ra0 = ldA8f(Af, (long long)(m0 + r) * K + ck);
        ra1 = ldA8f(Af, (long long)(m0 + r + 64) * K + ck);
        rb0 = *reinterpret_cast<const int4*>(Wp + (long long)r * K + ck);
        rb1 = *reinterpret_cast<const int4*>(Wp + (long long)(r + 64) * K + ck);
        for (int k0 = 0; k0 < K; k0 += 32, cur ^= 1) {
            *reinterpret_cast<int4*>(&As[cur][r][ck]) = ra0;
            *reinterpret_cast<int4*>(&As[cur][r + 64][ck]) = ra1;
            *reinterpret_cast<int4*>(&Bs[cur][r][ck]) = rb0;
            *reinterpret_cast<int4*>(&Bs[cur][r + 64][ck]) = rb1;
            __syncthreads();
            if (k0 + 32 < K) {
                const int kn = k0 + 32 + ck;
                ra0 = ldA8f(Af, (long long)(m0 + r) * K + kn);
                ra1 = ldA8f(Af, (long long)(m0 + r + 64) * K + kn);
                rb0 = *reinterpret_cast<const int4*>(Wp + (long long)r * K + kn);
                rb1 = *reinterpret_cast<const int4*>(Wp + (long long)(r + 64) * K + kn);
            }
            const int lr = lane & 15, lk = (lane >> 4) * 8;
            bf16x8 af[4], bfr[4];
#pragma unroll
            for (int i = 0; i < 4; ++i) {
                af[i]  = *reinterpret_cast<const bf16x8*>(&As[cur][wm * 64 + i * 16 + lr][lk]);
                bfr[i] = *reinterpret_cast<const bf16x8*>(&Bs[cur][wn * 64 + i * 16 + lr][lk]);
            }
#pragma unroll
            for (int i = 0; i < 4; ++i)
#pragma unroll
                for (int j = 0; j < 4; ++j)
                    acc[i][j] = __builtin_amdgcn_mfma_f32_16x16x32_bf16(
                        af[i], bfr[j], acc[i][j], 0, 0, 0);
        }
    }

    const int lr = lane & 15, lrow4 = (lane >> 4) * 4;
#pragma unroll
    for (int j = 0; j < 4; ++j) {
        const int col = n0 + wn * 64 + j * 16 + lr;
        if (col >= Nreal) continue;
        float bsum = 0.f;
        if (bias1) bsum += bias1[col];
        if (bias2) bsum += bias2[col];
#pragma unroll
        for (int i = 0; i < 4; ++i) {
#pragma unroll
            for (int rr = 0; rr < 4; ++rr) {
                const int row = m0 + wm * 64 + i * 16 + lrow4 + rr;
                float v = acc[i][j][rr] + bsum;
                if (ACT == 1) v = fast_tanh(v);
                if (ACT == 2) v = fmaxf(v, 0.f);
                if (OUTBF)
                    ((unsigned short*)C)[(long long)row * ldc + col] = f2bf(v);
                else
                    ((float*)C)[(long long)row * ldc + col] = v;
            }
        }
    }
}

static void mgemm(hipStream_t s, int act, int outbf, int af32,
                  const void* A, const unsigned short* W,
                  const float* b1, const float* b2,
                  void* C, long long ldc, int M, int Nreal, int K)
{
    dim3 grid((Nreal + 127) / 128, M / 128), blk(256);
#define MG(a, o, f) mfma_gemm<a, o, f><<<grid, blk, 0, s>>>(A, W, b1, b2, C, ldc, Nreal, K)
    if (af32) {
        if (outbf) { if (act == 1) MG(1,1,1); else if (act == 2) MG(2,1,1); else MG(0,1,1); }
        else       { if (act == 1) MG(1,0,1); else if (act == 2) MG(2,0,1); else MG(0,0,1); }
    } else {
        if (outbf) { if (act == 1) MG(1,1,0); else if (act == 2) MG(2,1,0); else MG(0,1,0); }
        else       { if (act == 1) MG(1,0,0); else if (act == 2) MG(2,0,0); else MG(0,0,0); }
    }
#undef MG
}

// ---------------------------------------------------------------------------
// dec2: 256x256 tile, BK=64, 512 threads (8 waves 2Mx4N), 128 KB LDS dbuf,
// 4 phases/K-tile, raw s_barrier + counted vmcnt(8) pipeline (tile t+2's
// loads issue in tile t's phase 3, after a barrier proves the buffer free).
// A [5120][2048] bf16, W [9216][2048] bf16, C [5120][8964] fp32 + bias.
// ---------------------------------------------------------------------------
__global__ __launch_bounds__(512, 1) void gemm256_kernel(
    const unsigned short* __restrict__ A, const unsigned short* __restrict__ W,
    const float* __restrict__ bias, float* __restrict__ C)
{
    __shared__ __align__(16) unsigned short As[2][256][64];
    __shared__ __align__(16) unsigned short Bs[2][256][64];
    const int tid = threadIdx.x;
    const int lane = tid & 63;
    const int wave = tid >> 6;          // 0..7
    const int wm = wave >> 2, wn = wave & 3;
    const int lr = lane & 15, hi = lane >> 4;
    const int K = 2048;

    // bijective XCD swizzle + MI=2 L2-blocked walk over grid (36 x 20)
    const int nwg = gridDim.x * gridDim.y;
    const int orig = blockIdx.y * gridDim.x + blockIdx.x;
    const int xcd = orig & 7, base = orig >> 3;
    const int q8 = nwg >> 3, r8 = nwg & 7;
    const int wg = (xcd < r8 ? xcd * (q8 + 1) : r8 * (q8 + 1) + (xcd - r8) * q8) + base;
    const int MI = 2;
    const int slabSz = gridDim.x * MI;          // 72
    int m0, n0;
    {
        const int mb = wg / slabSz, rem = wg % slabSz;
        m0 = (mb * MI + rem % MI) * 256;
        n0 = (rem / MI) * 256;
    }

    // staging: chunk c (0..31) = rows 8c..8c+7 of the 256x64 tile (1KB)
    const int srow = lane >> 3;
    const int scol = (lane & 7) * 8;
    auto stage = [&](int kt, int b) {
#pragma unroll
        for (int q = 0; q < 4; ++q) {
            const int c = wave * 4 + q;
            const unsigned short* ga = A + (long long)(m0 + 8 * c + srow) * K + kt * 64 + scol;
            GLD16(ga, (char*)&As[b][0][0] + c * 1024);
        }
#pragma unroll
        for (int q = 0; q < 4; ++q) {
            const int c = wave * 4 + q;
            const unsigned short* gw = W + (long long)(n0 + 8 * c + srow) * K + kt * 64 + scol;
            GLD16(gw, (char*)&Bs[b][0][0] + c * 1024);
        }
    };

    f32x4 acc[8][4] = {};
    const int nt = K / 64;   // 32
    stage(0, 0);
    stage(1, 1);

    for (int t = 0; t < nt; ++t) {
        const int b = t & 1;
        if (t + 1 < nt) asm volatile("s_waitcnt vmcnt(8)" ::: "memory");
        else            asm volatile("s_waitcnt vmcnt(0)" ::: "memory");
        __builtin_amdgcn_s_barrier();   // all waves' tile-t loads landed

        // phases 0..2: (mh,ks) = (0,0),(1,0),(0,1)
#pragma unroll
        for (int p = 0; p < 3; ++p) {
            const int mh = p & 1, ks = p >> 1;
            bf16x8 af[4], bfr[4];
#pragma unroll
            for (int i = 0; i < 4; ++i) {
                af[i]  = *reinterpret_cast<const bf16x8*>(
                    &As[b][wm * 128 + mh * 64 + i * 16 + lr][ks * 32 + hi * 8]);
                bfr[i] = *reinterpret_cast<const bf16x8*>(
                    &Bs[b][wn * 64 + i * 16 + lr][ks * 32 + hi * 8]);
            }
            __builtin_amdgcn_s_setprio(1);
#pragma unroll
            for (int i = 0; i < 4; ++i)
#pragma unroll
                for (int j = 0; j < 4; ++j)
                    acc[mh * 4 + i][j] = __builtin_amdgcn_mfma_f32_16x16x32_bf16(
                        af[i], bfr[j], acc[mh * 4 + i][j], 0, 0, 0);
            __builtin_amdgcn_s_setprio(0);
            __builtin_amdgcn_s_barrier();
        }
        // phase 3: (mh,ks) = (1,1); read; lgkmcnt(0)+sched_barrier pins the
        // ds_reads BEFORE the barrier (rule #18); then barrier -> buffer b is
        // free -> stage tile t+2 into it -> MFMA on the register values.
        {
            bf16x8 af[4], bfr[4];
#pragma unroll
            for (int i = 0; i < 4; ++i) {
                af[i]  = *reinterpret_cast<const bf16x8*>(
                    &As[b][wm * 128 + 64 + i * 16 + lr][32 + hi * 8]);
                bfr[i] = *reinterpret_cast<const bf16x8*>(
                    &Bs[b][wn * 64 + i * 16 + lr][32 + hi * 8]);
            }
            asm volatile("s_waitcnt lgkmcnt(0)" ::: "memory");
            __builtin_amdgcn_sched_barrier(0);
            __builtin_amdgcn_s_barrier();   // all waves done reading buf b
            if (t + 2 < nt) stage(t + 2, b);
            __builtin_amdgcn_s_setprio(1);
#pragma unroll
            for (int i = 0; i < 4; ++i)
#pragma unroll
                for (int j = 0; j < 4; ++j)
                    acc[4 + i][j] = __builtin_amdgcn_mfma_f32_16x16x32_bf16(
                        af[i], bfr[j], acc[4 + i][j], 0, 0, 0);
            __builtin_amdgcn_s_setprio(0);
        }
    }

    // epilogue: row = m0 + wm*128 + i8*16 + hi*4 + rr ; col = n0 + wn*64 + j*16 + lr
#pragma unroll
    for (int j = 0; j < 4; ++j) {
        const int col = n0 + wn * 64 + j * 16 + lr;
        if (col >= V_) continue;
        const float bsum = bias[col];
#pragma unroll
        for (int i8 = 0; i8 < 8; ++i8) {
#pragma unroll
            for (int rr = 0; rr < 4; ++rr) {
                const int row = m0 + wm * 128 + i8 * 16 + hi * 4 + rr;
                C[(long long)row * V_ + col] = acc[i8][j][rr] + bsum;
            }
        }
    }
}

// ---------------------------------------------------------------------------
// MEGA kernel (unchanged from round 16).
// ---------------------------------------------------------------------------
#define LSTM_ISSUE(b_, dst_) do {                                              \
    const unsigned short* pa_ = (((b_) >> 2) ? q20 : q10) + ((b_) & 3) * 128;  \
    const unsigned short* pb_ = (((b_) >> 2) ? q21 : q11) + ((b_) & 3) * 128;  \
    asm volatile(                                                              \
        "global_load_dwordx4 %0, %[pa], off sc0 sc1\n\t"                       \
        "global_load_dwordx4 %1, %[pa], off offset:64 sc0 sc1\n\t"             \
        "global_load_dwordx4 %2, %[pa], off offset:128 sc0 sc1\n\t"            \
        "global_load_dwordx4 %3, %[pa], off offset:192 sc0 sc1\n\t"            \
        "global_load_dwordx4 %4, %[pb], off sc0 sc1\n\t"                       \
        "global_load_dwordx4 %5, %[pb], off offset:64 sc0 sc1\n\t"             \
        "global_load_dwordx4 %6, %[pb], off offset:128 sc0 sc1\n\t"            \
        "global_load_dwordx4 %7, %[pb], off offset:192 sc0 sc1"                \
        : "=&v"((dst_)[0]), "=&v"((dst_)[1]), "=&v"((dst_)[2]), "=&v"((dst_)[3]), \
          "=&v"((dst_)[4]), "=&v"((dst_)[5]), "=&v"((dst_)[6]), "=&v"((dst_)[7])  \
        : [pa] "v"(pa_), [pb] "v"(pb_)                                         \
        : "memory");                                                           \
} while (0)

__global__ __launch_bounds__(256, 1) void mega_kernel(
    const unsigned short* __restrict__ emb_bf,
    const unsigned short* __restrict__ Wih0p, const unsigned short* __restrict__ Whh0p,
    const unsigned short* __restrict__ Wih1p, const unsigned short* __restrict__ Whh1p,
    const float* __restrict__ bp0, const float* __restrict__ bp1,
    const float* __restrict__ c0,
    unsigned short* __restrict__ hbuf,
    float* __restrict__ st_h, float* __restrict__ st_c,
    unsigned short* __restrict__ h_top,
    int* flags,
    const float* __restrict__ question, const float* __restrict__ history,
    const float* __restrict__ image,
    const unsigned short* __restrict__ Wq_bf, const unsigned short* __restrict__ Wh_bf,
    const unsigned short* __restrict__ Wi_bf,
    const float* __restrict__ bq, const float* __restrict__ bhb,
    const float* __restrict__ bi,
    unsigned short* __restrict__ q_emb, unsigned short* __restrict__ h_emb,
    unsigned short* __restrict__ i_emb)
{
    __shared__ __align__(16) char smem[131072];
    const int gid = blockIdx.x;
    const int tid = threadIdx.x;

    if (gid >= MEGA_LSTM_) {
        int g = gid - MEGA_LSTM_;
        const float* A; const unsigned short* W; const float* bias;
        unsigned short* Cc;
        if (g < MEGA_CTXQ_)       { A = question; W = Wq_bf; bias = bq;  Cc = q_emb; }
        else if (g < MEGA_CTXQ_ + MEGA_CTXH_) {
            g -= MEGA_CTXQ_;        A = history;  W = Wh_bf; bias = bhb; Cc = h_emb; }
        else { g -= MEGA_CTXQ_ + MEGA_CTXH_; A = image; W = Wi_bf; bias = bi; Cc = i_emb; }
        const int m0 = (g >> 2) * 128, n0 = (g & 3) * 128;
        const int K = 1024;

        unsigned short (*As)[128][32] = (unsigned short (*)[128][32])smem;
        unsigned short (*Bs)[128][32] = (unsigned short (*)[128][32])(smem + 16384);
        const int lane = tid & 63;
        const int wave = tid >> 6;
        const int wm = wave >> 1, wn = wave & 1;
        const int r = tid >> 2;
        const int ck = (tid & 3) * 8;
        const unsigned short* Wp = W + (long long)n0 * K;

        f32x4 acc[4][4] = {};
        int4 ra0, ra1, rb0, rb1;
        ra0 = ldA8f(A, (long long)(m0 + r) * K + ck);
        ra1 = ldA8f(A, (long long)(m0 + r + 64) * K + ck);
        rb0 = *reinterpret_cast<const int4*>(Wp + (long long)r * K + ck);
        rb1 = *reinterpret_cast<const int4*>(Wp + (long long)(r + 64) * K + ck);
        int cur = 0;
        for (int k0 = 0; k0 < K; k0 += 32, cur ^= 1) {
            *reinterpret_cast<int4*>(&As[cur][r][ck]) = ra0;
            *reinterpret_cast<int4*>(&As[cur][r + 64][ck]) = ra1;
            *reinterpret_cast<int4*>(&Bs[cur][r][ck]) = rb0;
            *reinterpret_cast<int4*>(&Bs[cur][r + 64][ck]) = rb1;
            __syncthreads();
            if (k0 + 32 < K) {
                const int kn = k0 + 32 + ck;
                ra0 = ldA8f(A, (long long)(m0 + r) * K + kn);
                ra1 = ldA8f(A, (long long)(m0 + r + 64) * K + kn);
                rb0 = *reinterpret_cast<const int4*>(Wp + (long long)r * K + kn);
                rb1 = *reinterpret_cast<const int4*>(Wp + (long long)(r + 64) * K + kn);
            }
            const int lr = lane & 15, lk = (lane >> 4) * 8;
            bf16x8 af[4], bfr[4];
#pragma unroll
            for (int i = 0; i < 4; ++i) {
                af[i]  = *reinterpret_cast<const bf16x8*>(&As[cur][wm * 64 + i * 16 + lr][lk]);
                bfr[i] = *reinterpret_cast<const bf16x8*>(&Bs[cur][wn * 64 + i * 16 + lr][lk]);
            }
#pragma unroll
            for (int i = 0; i < 4; ++i)
#pragma unroll
                for (int j = 0; j < 4; ++j)
                    acc[i][j] = __builtin_amdgcn_mfma_f32_16x16x32_bf16(
                        af[i], bfr[j], acc[i][j], 0, 0, 0);
        }
        const int lr = lane & 15, lrow4 = (lane >> 4) * 4;
#pragma unroll
        for (int j = 0; j < 4; ++j) {
            const int col = n0 + wn * 64 + j * 16 + lr;
            const float bsum = bias[col];
#pragma unroll
            for (int i = 0; i < 4; ++i)
#pragma unroll
                for (int rr = 0; rr < 4; ++rr) {
                    const int row = m0 + wm * 64 + i * 16 + lrow4 + rr;
                    Cc[(long long)row * 512 + col] = f2bf(acc[i][j][rr] + bsum);
                }
        }
        return;
    }

    const int grp = gid >> 6;
    const int id  = gid & 63;
    const int mt = id >> 5, nt = id & 31;
    const int m0 = mt * 128, n0 = nt * 64;
    const int lane = tid & 63;
    const int w = tid >> 6;
    const int lr = lane & 15;
    const int hi = lane >> 4;
    const int hi4 = hi * 4;

    const unsigned short* W1g = (grp ? Wih1p : Wih0p) + (long long)n0 * H_;
    const unsigned short* W2g = (grp ? Whh1p : Whh0p) + (long long)n0 * H_;

#pragma unroll
    for (int it = 0; it < 16; ++it) {
        const int e = (tid + it * 256) * 8;
        const int row = e >> 9, col = e & 511;
        const int bir = (col * 2) ^ ((row & 7) << 4);
        char* dst = smem + row * 1024 + bir;
        *reinterpret_cast<int4*>(dst) =
            *reinterpret_cast<const int4*>(W1g + (long long)row * H_ + col);
        *reinterpret_cast<int4*>(dst + 65536) =
            *reinterpret_cast<const int4*>(W2g + (long long)row * H_ + col);
    }
    __syncthreads();

    const int h = nt * 16 + lr;
    const float* bp = grp ? bp1 : bp0;
    float bg[4];
#pragma unroll
    for (int g = 0; g < 4; ++g) bg[g] = bp[n0 + g * 16 + lr];

    const int ar0 = m0 + w * 32 + lr;
    const int ar1 = ar0 + 16;

    float cregA[4], cregB[4], hn0[4], hn1[4];
#pragma unroll
    for (int rr = 0; rr < 4; ++rr) {
        cregA[rr] = c0[(long long)grp * BH_ + (long long)(m0 + w * 32 + hi4 + rr) * H_ + h];
        cregB[rr] = c0[(long long)grp * BH_ + (long long)(m0 + w * 32 + 16 + hi4 + rr) * H_ + h];
    }

    int bbase[4];
#pragma unroll
    for (int j = 0; j < 4; ++j)
        bbase[j] = (j * 16 + lr) * 1024 + ((hi * 16) ^ ((lr & 3) << 4));
    const int xk6 = ((lr >> 2) & 1) << 6;

    int* myFlag = flags + (mt * 64 + grp * 32 + nt) * 16;
    const long long sEmb = (long long)T_ * H_;

    for (int s = 0; s <= T_; ++s) {
        const bool active = (grp == 0) ? (s < T_) : (s >= 1);
        const int t = grp ? (s - 1) : s;
        if (active) {
            const unsigned short *A1, *A2;
            long long sA1;
            unsigned short* hout;
            if (grp == 0) {
                A1 = emb_bf + (long long)t * H_; sA1 = sEmb;
                A2 = hbuf + (long long)(s % 3) * BH_;
                hout = hbuf + (long long)((s + 1) % 3) * BH_;
            } else {
                A1 = hbuf + (long long)(s % 3) * BH_; sA1 = H_;
                A2 = hbuf + (long long)(3 + (s & 1)) * BH_;
                hout = hbuf + (long long)(3 + ((s + 1) & 1)) * BH_;
            }
            const unsigned short* q10 = A1 + (long long)ar0 * sA1 + hi * 8;
            const unsigned short* q11 = A1 + (long long)ar1 * sA1 + hi * 8;
            const unsigned short* q20 = A2 + (long long)ar0 * H_ + hi * 8;
            const unsigned short* q21 = A2 + (long long)ar1 * H_ + hi * 8;

            int4 buf[3][8];
            LSTM_ISSUE(0, buf[0]);
            LSTM_ISSUE(1, buf[1]);
            LSTM_ISSUE(2, buf[2]);

            f32x4 accA[4] = {}, accB[4] = {};
#pragma unroll
            for (int b = 0; b < 8; ++b) {
                if (b < 6)      asm volatile("s_waitcnt vmcnt(16)" ::: "memory");
                else if (b == 6) asm volatile("s_waitcnt vmcnt(8)" ::: "memory");
                else             asm volatile("s_waitcnt vmcnt(0)" ::: "memory");
                __builtin_amdgcn_sched_barrier(0);
#pragma unroll
                for (int i = 0; i < 4; ++i) {
                    const int it = b * 4 + i;
                    const int kk = it & 15, p = it >> 4;
                    const bf16x8 a0 = *reinterpret_cast<const bf16x8*>(&buf[b % 3][i]);
                    const bf16x8 a1 = *reinterpret_cast<const bf16x8*>(&buf[b % 3][4 + i]);
                    const int kb = ((kk << 6) ^ xk6) + (p << 16);
#pragma unroll
                    for (int j = 0; j < 4; ++j) {
                        const bf16x8 bfv = *reinterpret_cast<const bf16x8*>(
                            smem + bbase[j] + kb);
                        accA[j] = __builtin_amdgcn_mfma_f32_16x16x32_bf16(a0, bfv, accA[j], 0, 0, 0);
                        accB[j] = __builtin_amdgcn_mfma_f32_16x16x32_bf16(a1, bfv, accB[j], 0, 0, 0);
                    }
                }
                if (b + 3 < 8) LSTM_ISSUE(b + 3, buf[b % 3]);
            }

#pragma unroll
            for (int rr = 0; rr < 4; ++rr) {
                {
                    const int b = m0 + w * 32 + hi4 + rr;
                    const float i_ = fast_sigmoid(accA[0][rr] + bg[0]);
                    const float f_ = fast_sigmoid(accA[1][rr] + bg[1]);
                    const float g_ = fast_tanh(accA[2][rr] + bg[2]);
                    const float o_ = fast_sigmoid(accA[3][rr] + bg[3]);
                    const float cn = f_ * cregA[rr] + i_ * g_;
                    const float hn = o_ * fast_tanh(cn);
                    cregA[rr] = cn; hn0[rr] = hn;
                    st16_sc(&hout[(long long)b * H_ + h], f2bf(hn));
                }
                {
                    const int b = m0 + w * 32 + 16 + hi4 + rr;
                    const float i_ = fast_sigmoid(accB[0][rr] + bg[0]);
                    const float f_ = fast_sigmoid(accB[1][rr] + bg[1]);
                    const float g_ = fast_tanh(accB[2][rr] + bg[2]);
                    const float o_ = fast_sigmoid(accB[3][rr] + bg[3]);
                    const float cn = f_ * cregB[rr] + i_ * g_;
                    const float hn = o_ * fast_tanh(cn);
                    cregB[rr] = cn; hn1[rr] = hn;
                    st16_sc(&hout[(long long)b * H_ + h], f2bf(hn));
                }
            }
            if (s == T_) {
#pragma unroll
                for (int rr = 0; rr < 4; ++rr) {
                    const int b0r = m0 + w * 32 + hi4 + rr;
                    const int b1r = b0r + 16;
                    h_top[((long long)b0r * T_ + t) * H_ + h] = f2bf(hn0[rr]);
                    h_top[((long long)b1r * T_ + t) * H_ + h] = f2bf(hn1[rr]);
                    st_h[(long long)grp * BH_ + (long long)b0r * H_ + h] = hn0[rr];
                    st_h[(long long)grp * BH_ + (long long)b1r * H_ + h] = hn1[rr];
                    st_c[(long long)grp * BH_ + (long long)b0r * H_ + h] = cregA[rr];
                    st_c[(long long)grp * BH_ + (long long)b1r * H_ + h] = cregB[rr];
                }
            }
        }
        if (s < T_) {
            __syncthreads();
            if (tid == 0) {
                int v = s + 1;
                asm volatile("global_store_dword %0, %1, off sc0 sc1"
                             :: "v"(myFlag), "v"(v) : "memory");
            }
            if (active) {
#pragma unroll
                for (int rr = 0; rr < 4; ++rr) {
                    const int b0r = m0 + w * 32 + hi4 + rr;
                    const int b1r = b0r + 16;
                    if (grp == 1) {
                        h_top[((long long)b0r * T_ + t) * H_ + h] = f2bf(hn0[rr]);
                        h_top[((long long)b1r * T_ + t) * H_ + h] = f2bf(hn1[rr]);
                    }
                    if (t == T_ - 1) {
                        st_h[(long long)grp * BH_ + (long long)b0r * H_ + h] = hn0[rr];
                        st_h[(long long)grp * BH_ + (long long)b1r * H_ + h] = hn1[rr];
                        st_c[(long long)grp * BH_ + (long long)b0r * H_ + h] = cregA[rr];
                        st_c[(long long)grp * BH_ + (long long)b1r * H_ + h] = cregB[rr];
                    }
                }
            }
            if (tid < 64) {
                const int thr = (grp == 0 && tid >= 32) ? s : s + 1;
                const int* fp = flags + (mt * 64 + tid) * 16;
                while (ld32_sc(fp) < thr) __builtin_amdgcn_s_sleep(2);
            }
            __syncthreads();
        }
    }
}

// ---------------------------------------------------------------------------
// Triple attention (unchanged).
// ---------------------------------------------------------------------------
__global__ __launch_bounds__(256) void attend3_kernel(
    const unsigned short* __restrict__ q_emb, const unsigned short* __restrict__ h_emb,
    const unsigned short* __restrict__ i_emb,
    const float* __restrict__ proj3,
    const float* __restrict__ waq, const float* __restrict__ baq, const float* __restrict__ bansq,
    const float* __restrict__ wah, const float* __restrict__ bah, const float* __restrict__ bansh,
    const float* __restrict__ wai, const float* __restrict__ bai, const float* __restrict__ bansi,
    const unsigned short* __restrict__ h_top,
    unsigned short* __restrict__ fcat, unsigned short* __restrict__ fusion)
{
    __shared__ float p_lds[512];
    __shared__ float wa_lds[512];
    __shared__ float lg[96];
    const int bt0 = blockIdx.x;
    const int bt = (bt0 & 7) * (BT_ / 8) + (bt0 >> 3);
    const int c = blockIdx.y;
    const int b = bt / T_;
    const int tid = threadIdx.x;
    const int wid = tid >> 6, lane = tid & 63;

    if (c == 0 && tid < 64)
        *reinterpret_cast<u16x8*>(&fusion[(long long)bt * 1024 + tid * 8]) =
            *reinterpret_cast<const u16x8*>(&h_top[(long long)bt * 512 + tid * 8]);

    const unsigned short* ctx = c == 0 ? q_emb : c == 1 ? h_emb : i_emb;
    const int Lx = c == 0 ? LQ_ : c == 1 ? LH_ : LI_;
    const float* wa = c == 0 ? waq : c == 1 ? wah : wai;
    const float bav = (c == 0 ? baq : c == 1 ? bah : bai)[0];
    const float* bans = c == 0 ? bansq : c == 1 ? bansh : bansi;

    p_lds[tid]       = proj3[(long long)bt * 1536 + c * 512 + tid] + bans[tid];
    p_lds[tid + 256] = proj3[(long long)bt * 1536 + c * 512 + tid + 256] + bans[tid + 256];
    wa_lds[tid] = wa[tid];
    wa_lds[tid + 256] = wa[tid + 256];
    __syncthreads();

    for (int l = wid; l < Lx; l += 4) {
        const unsigned short* crow = ctx + ((long long)b * Lx + l) * H_;
        float acc = 0.f;
#pragma unroll
        for (int j = 0; j < 8; ++j) {
            const int hp = lane + 64 * j;
            acc += wa_lds[hp] * fast_tanh(bf2f(crow[hp]) + p_lds[hp]);
        }
        for (int o = 32; o > 0; o >>= 1) acc += __shfl_down(acc, o);
        if (lane == 0) lg[l] = acc + bav;
    }
    __syncthreads();
    if (tid == 0) {
        float m = -1e30f;
        for (int l = 0; l < Lx; ++l) m = fmaxf(m, lg[l]);
        float ssum = 0.f;
        for (int l = 0; l < Lx; ++l) { const float e = __expf(lg[l] - m); lg[l] = e; ssum += e; }
        const float inv = __builtin_amdgcn_rcpf(ssum);
        for (int l = 0; l < Lx; ++l) lg[l] *= inv;
    }
    __syncthreads();
    for (int hp = tid; hp < H_; hp += 256) {
        float acc = 0.f;
        for (int l = 0; l < Lx; ++l)
            acc += lg[l] * bf2f(ctx[((long long)b * Lx + l) * H_ + hp]);
        fcat[(long long)bt * 1536 + c * 512 + hp] = f2bf(acc);
    }
}

// In-place log_softmax(BETA * x) per row of V_; row cached in registers.
__global__ __launch_bounds__(256) void log_softmax_kernel(float* __restrict__ out)
{
    __shared__ float red[4];
    __shared__ float bc;
    const long long base = (long long)blockIdx.x * V_;
    const int tid = threadIdx.x, lane = tid & 63, wid = tid >> 6;

    float r[36];
    float m = -1e30f;
#pragma unroll
    for (int i = 0; i < 36; ++i) {
        const int v = tid + i * 256;
        r[i] = (v < V_) ? BETA_ * out[base + v] : -1e30f;
        m = fmaxf(m, r[i]);
    }
    for (int o = 32; o > 0; o >>= 1) m = fmaxf(m, __shfl_down(m, o));
    if (lane == 0) red[wid] = m;
    __syncthreads();
    if (tid == 0)
        bc = fmaxf(fmaxf(red[0], red[1]), fmaxf(red[2], red[3]));
    __syncthreads();
    m = bc;

    float s = 0.f;
#pragma unroll
    for (int i = 0; i < 36; ++i) s += __expf(r[i] - m);
    for (int o = 32; o > 0; o >>= 1) s += __shfl_down(s, o);
    if (lane == 0) red[wid] = s;
    __syncthreads();
    if (tid == 0) bc = m + logf(red[0] + red[1] + red[2] + red[3]);
    __syncthreads();
    const float ls = bc;
#pragma unroll
    for (int i = 0; i < 36; ++i) {
        const int v = tid + i * 256;
        if (v < V_) out[base + v] = r[i] - ls;
    }
}

// ---------------------------------------------------------------------------
extern "C" void kernel_launch(void* const* d_in, const int* in_sizes, int n_in,
                              void* d_out_, int out_size, void* d_ws, size_t ws_size,
                              hipStream_t stream)
{
    const float* emb      = (const float*)d_in[0];
    const float* question = (const float*)d_in[1];
    const float* history  = (const float*)d_in[2];
    const float* image    = (const float*)d_in[3];
    const float* h0       = (const float*)d_in[4];
    const float* c0       = (const float*)d_in[5];
    const float* Wih      = (const float*)d_in[6];
    const float* Whh      = (const float*)d_in[7];
    const float* bih      = (const float*)d_in[8];
    const float* bhh      = (const float*)d_in[9];
    const float* Wq    = (const float*)d_in[10]; const float* bq    = (const float*)d_in[11];
    const float* Wansq = (const float*)d_in[12]; const float* bansq = (const float*)d_in[13];
    const float* waq   = (const float*)d_in[14]; const float* baq   = (const float*)d_in[15];
    const float* Wh    = (const float*)d_in[16]; const float* bh    = (const float*)d_in[17];
    const float* Wansh = (const float*)d_in[18]; const float* bansh = (const float*)d_in[19];
    const float* wah   = (const float*)d_in[20]; const float* bah   = (const float*)d_in[21];
    const float* Wi    = (const float*)d_in[22]; const float* bi    = (const float*)d_in[23];
    const float* Wansi = (const float*)d_in[24]; const float* bansi = (const float*)d_in[25];
    const float* wai   = (const float*)d_in[26]; const float* bai   = (const float*)d_in[27];
    const float* Wcat  = (const float*)d_in[28]; const float* bcat  = (const float*)d_in[29];
    const float* Wd1   = (const float*)d_in[30]; const float* bd1   = (const float*)d_in[31];
    const float* Wd2   = (const float*)d_in[32]; const float* bd2   = (const float*)d_in[33];

    float* out = (float*)d_out_;

    // ---- workspace layout ----
    int*   flags = (int*)d_ws;
    float* st_h = (float*)((char*)d_ws + 8192);
    float* st_c = st_h + 2LL * BH_;
    float* bp0  = st_c + 2LL * BH_;
    float* bp1  = bp0 + 2048;
    unsigned short* hbuf   = (unsigned short*)(bp1 + 2048);
    unsigned short* Wih0p  = hbuf + 5LL * BH_;
    unsigned short* Whh0p  = Wih0p + 2048LL * H_;
    unsigned short* Wih1p  = Whh0p + 2048LL * H_;
    unsigned short* Whh1p  = Wih1p + 2048LL * H_;
    unsigned short* emb_bf = Whh1p + 2048LL * H_;
    unsigned short* h_top_bf = emb_bf + (long long)BT_ * H_;
    unsigned short* q_emb_bf = h_top_bf + (long long)BT_ * H_;
    unsigned short* h_emb_bf = q_emb_bf + (long long)B_ * LQ_ * H_;
    unsigned short* i_emb_bf = h_emb_bf + (long long)B_ * LH_ * H_;
    unsigned short* dec1_bf  = i_emb_bf + (long long)B_ * LI_ * H_;
    unsigned short* Wd2p_bf  = dec1_bf + (long long)BT_ * 4 * H_;   // NPAD_*2048

    // ---- scratch inside d_out ----
    unsigned short* Wq_bf    = (unsigned short*)out;
    unsigned short* Wh_bf    = Wq_bf + 524288;
    unsigned short* Wi_bf    = Wh_bf + 524288;
    unsigned short* Wansq_bf = Wi_bf + 524288;
    unsigned short* Wansh_bf = Wansq_bf + 262144;
    unsigned short* Wansi_bf = Wansh_bf + 262144;
    unsigned short* Wcat_bf  = Wansi_bf + 262144;
    unsigned short* Wd1_bf   = Wcat_bf + 786432;
    float* proj3 = (float*)(Wd1_bf + 2097152);
    unsigned short* fcat_bf   = (unsigned short*)(proj3 + (long long)BT_ * 1536);
    unsigned short* fusion_bf = fcat_bf + (long long)BT_ * 1536;

    // 1) ALL prep in ONE launch
    {
        PrepArgs a;
        a.wsrc[0] = Wq;    a.wdst[0] = Wq_bf;
        a.wsrc[1] = Wh;    a.wdst[1] = Wh_bf;
        a.wsrc[2] = Wi;    a.wdst[2] = Wi_bf;
        a.wsrc[3] = Wansq; a.wdst[3] = Wansq_bf;
        a.wsrc[4] = Wansh; a.wdst[4] = Wansh_bf;
        a.wsrc[5] = Wansi; a.wdst[5] = Wansi_bf;
        a.wsrc[6] = Wcat;  a.wdst[6] = Wcat_bf;
        a.wsrc[7] = Wd1;   a.wdst[7] = Wd1_bf;
        a.Wd2 = Wd2; a.Wd2p = Wd2p_bf;
        a.emb = emb; a.emb_bf = emb_bf;
        a.psrc[0] = Wih;               a.pdst[0] = Wih0p;
        a.psrc[1] = Whh;               a.pdst[1] = Whh0p;
        a.psrc[2] = Wih + 2048LL * H_; a.pdst[2] = Wih1p;
        a.psrc[3] = Whh + 2048LL * H_; a.pdst[3] = Whh1p;
        a.h0 = h0; a.hbuf = hbuf;
        a.bih = bih; a.bhh = bhh; a.bp0 = bp0; a.bp1 = bp1;
        prep_kernel<<<dim3(PREP_GRID_), dim3(256), 0, stream>>>(a);
    }
    hipMemsetAsync(flags, 0, 8192, stream);

    // 2) MEGA: persistent LSTM (blocks 0-127) || ctx projections
    mega_kernel<<<dim3(MEGA_GRID_), dim3(256), 0, stream>>>(
        emb_bf, Wih0p, Whh0p, Wih1p, Whh1p, bp0, bp1, c0,
        hbuf, st_h, st_c, h_top_bf, flags,
        question, history, image, Wq_bf, Wh_bf, Wi_bf, bq, bh, bi,
        q_emb_bf, h_emb_bf, i_emb_bf);

    // 3) attention: one proj GEMM (N=1536) + attend3 grid (BT,3)
    mgemm(stream, 0, 0, 0, h_top_bf, Wansq_bf, nullptr, nullptr, proj3, 1536, BT_, 1536, H_);
    attend3_kernel<<<dim3(BT_, 3), dim3(256), 0, stream>>>(
        q_emb_bf, h_emb_bf, i_emb_bf, proj3,
        waq, baq, bansq, wah, bah, bansh, wai, bai, bansi,
        h_top_bf, fcat_bf, fusion_bf);

    // 4) fusion right half = tanh(fcat @ Wcat^T + bcat)
    mgemm(stream, 1, 1, 0, fcat_bf, Wcat_bf, bcat, nullptr, fusion_bf + H_, 2 * H_, BT_, H_, 3 * H_);

    // 5) decoder: dec1 (128-tile) then dec2 (8-phase 256-tile)
    mgemm(stream, 2, 1, 0, fusion_bf, Wd1_bf, bd1, nullptr, dec1_bf, 4 * H_, BT_, 4 * H_, 2 * H_);
    gemm256_kernel<<<dim3(NPAD_ / 256, BT_ / 256), dim3(512), 0, stream>>>(
        dec1_bf, Wd2p_bf, bd2, out);

    // 6) log_softmax
    log_softmax_kernel<<<dim3(BT_), dim3(256), 0, stream>>>(out);

    // 7) tail: hT, cT
    hipMemcpyAsync(out + (long long)BT_ * V_, st_h,
                   4LL * BH_ * sizeof(float), hipMemcpyDeviceToDevice, stream);
}

// Round 19
// 895.403 us; speedup vs baseline: 1.1164x; 1.1164x over previous
//
#include <hip/hip_runtime.h>
#include <cmath>

#define B_ 256
#define T_ 20
#define H_ 512
#define V_ 8964
#define LQ_ 40
#define LH_ 80
#define LI_ 49
#define BT_ (B_ * T_)   // 5120
#define BH_ (B_ * H_)   // 131072
#define NPAD_ 9216      // V_ padded to multiple of 256 (for 256-wide dec2 tiles)
#define BETA_ 3.0f

// mega-kernel block ranges (LSTM + ctx-projection helpers only)
#define MEGA_LSTM_ 128
#define MEGA_CTXQ_ 320
#define MEGA_CTXH_ 640
#define MEGA_CTXI_ 392
#define MEGA_CTX_ (MEGA_CTXQ_ + MEGA_CTXH_ + MEGA_CTXI_)   // 1352
#define MEGA_GRID_ (MEGA_LSTM_ + MEGA_CTX_)                // 1480

// prep-kernel block ranges
#define PREP_WCVT_ 2560           // 8 weights, 5,242,880 elems
#define PREP_WD2_  9216           // NPAD*2048 / 2048
#define PREP_EMB_  1280
#define PREP_PERM_ 2048
#define PREP_H0_   128
#define PREP_BIAS_ 2
#define PREP_GRID_ (PREP_WCVT_ + PREP_WD2_ + PREP_EMB_ + PREP_PERM_ + PREP_H0_ + PREP_BIAS_)

typedef __attribute__((ext_vector_type(8))) short bf16x8;
typedef __attribute__((ext_vector_type(4))) float f32x4;
typedef __attribute__((ext_vector_type(8))) unsigned short u16x8;

static __device__ __forceinline__ unsigned short f2bf(float f) {
    union { float f; unsigned u; } v; v.f = f;
    unsigned r = v.u + 0x7FFF + ((v.u >> 16) & 1);
    return (unsigned short)(r >> 16);
}
static __device__ __forceinline__ float bf2f(unsigned short u) {
    union { unsigned u; float f; } v; v.u = ((unsigned)u) << 16;
    return v.f;
}
static __device__ __forceinline__ float fast_tanh(float x) {
    const float e = __expf(2.f * x);
    return 1.f - 2.f * __builtin_amdgcn_rcpf(e + 1.f);
}
static __device__ __forceinline__ float fast_sigmoid(float x) {
    return __builtin_amdgcn_rcpf(1.f + __expf(-x));
}
static __device__ __forceinline__ void st16_sc(unsigned short* p, unsigned short v) {
    unsigned int vv = v;
    asm volatile("global_store_short %0, %1, off sc0 sc1" :: "v"(p), "v"(vv) : "memory");
}
static __device__ __forceinline__ int ld32_sc(const int* p) {
    int v;
    asm volatile("global_load_dword %0, %1, off sc0 sc1\n\t"
                 "s_waitcnt vmcnt(0)"
                 : "=v"(v) : "v"(p) : "memory");
    return v;
}
#define GLD16(g, l) __builtin_amdgcn_global_load_lds(                                   \
    (const __attribute__((address_space(1))) unsigned int*)(unsigned long long)(const void*)(g), \
    (__attribute__((address_space(3))) unsigned int*)(unsigned int)(unsigned long long)(void*)(l), \
    16, 0, 0)

static __device__ __forceinline__ u16x8 cvt8(const float* p)
{
    float4 a = *reinterpret_cast<const float4*>(p);
    float4 b = *reinterpret_cast<const float4*>(p + 4);
    u16x8 v;
    v[0] = f2bf(a.x); v[1] = f2bf(a.y); v[2] = f2bf(a.z); v[3] = f2bf(a.w);
    v[4] = f2bf(b.x); v[5] = f2bf(b.y); v[6] = f2bf(b.z); v[7] = f2bf(b.w);
    return v;
}

// ---------------------------------------------------------------------------
// Consolidated prep kernel.
// ---------------------------------------------------------------------------
struct PrepArgs {
    const float* wsrc[8]; unsigned short* wdst[8];
    const float* Wd2; unsigned short* Wd2p;
    const float* emb; unsigned short* emb_bf;
    const float* psrc[4]; unsigned short* pdst[4];
    const float* h0; unsigned short* hbuf;
    const float* bih; const float* bhh; float* bp0; float* bp1;
};

__global__ __launch_bounds__(256) void prep_kernel(PrepArgs a)
{
    static constexpr long long WSZ[8] = {524288, 524288, 524288, 262144,
                                         262144, 262144, 786432, 2097152};
    int g = blockIdx.x;
    const int tid = threadIdx.x;

    if (g < PREP_WCVT_) {
        long long off = (long long)g * 2048;
        int seg = 0;
#pragma unroll
        for (int i = 0; i < 8; ++i)
            if (seg == i && off >= WSZ[i]) { off -= WSZ[i]; ++seg; }
        const long long e = off + (long long)tid * 8;
        *reinterpret_cast<u16x8*>(a.wdst[seg] + e) = cvt8(a.wsrc[seg] + e);
        return;
    }
    g -= PREP_WCVT_;
    if (g < PREP_WD2_) {
        const long long e = (long long)g * 2048 + tid * 8;
        const long long row = e >> 11;
        u16x8 v;
        if (row < V_) v = cvt8(a.Wd2 + e);
        else v = (u16x8)0;
        *reinterpret_cast<u16x8*>(a.Wd2p + e) = v;
        return;
    }
    g -= PREP_WD2_;
    if (g < PREP_EMB_) {
        const long long e = (long long)g * 2048 + tid * 8;
        *reinterpret_cast<u16x8*>(a.emb_bf + e) = cvt8(a.emb + e);
        return;
    }
    g -= PREP_EMB_;
    if (g < PREP_PERM_) {
        const int which = g >> 9;
        const long long e0 = ((long long)(g & 511) * 256 + tid) * 8;
        const int drow = (int)(e0 >> 9);
        const int col = (int)(e0 & 511);
        const int gg = (drow >> 4) & 3;
        const int hsrc = ((drow >> 6) << 4) | (drow & 15);
        const int srow = (gg << 9) | hsrc;
        *reinterpret_cast<u16x8*>(a.pdst[which] + e0) =
            cvt8(a.psrc[which] + (long long)srow * 512 + col);
        return;
    }
    g -= PREP_PERM_;
    if (g < PREP_H0_) {
        const int half = g >> 6;
        const long long e = (long long)(g & 63) * 2048 + tid * 8;
        unsigned short* dst = a.hbuf + (half ? 4LL * BH_ : 0LL);
        *reinterpret_cast<u16x8*>(dst + e) = cvt8(a.h0 + (long long)half * BH_ + e);
        return;
    }
    g -= PREP_H0_;
    {
        const float* b1 = g ? a.bih + 2048 : a.bih;
        const float* b2 = g ? a.bhh + 2048 : a.bhh;
        float* dst = g ? a.bp1 : a.bp0;
#pragma unroll
        for (int i = 0; i < 8; ++i) {
            const int n = i * 256 + tid;
            const int gg = (n >> 4) & 3;
            const int h = ((n >> 6) << 4) | (n & 15);
            const int orig = (gg << 9) | h;
            dst[n] = b1[orig] + b2[orig];
        }
    }
}

// ---------------------------------------------------------------------------
static __device__ __forceinline__ int4 ldA8f(const float* A, long long idx)
{
    union { int4 i4; u16x8 v; } r;
    r.v = cvt8(A + idx);
    return r.i4;
}

// ---------------------------------------------------------------------------
// bf16 MFMA GEMM (128x128, BK=32, double-buffered, one barrier/K-step).
// Used for proj3 / Wcat / dec1.
// ---------------------------------------------------------------------------
template <int ACT, int OUTBF, int AF32>
__global__ __launch_bounds__(256, 2) void mfma_gemm(
    const void* __restrict__ A, const unsigned short* __restrict__ W,
    const float* __restrict__ bias1, const float* __restrict__ bias2,
    void* __restrict__ C, long long ldc, int Nreal, int K)
{
    __shared__ __align__(16) unsigned short As[2][128][32];
    __shared__ __align__(16) unsigned short Bs[2][128][32];
    const int tid = threadIdx.x;
    const int lane = tid & 63;
    const int wave = tid >> 6;
    const int wm = wave >> 1, wn = wave & 1;

    const int nwg = gridDim.x * gridDim.y;
    const int orig = blockIdx.y * gridDim.x + blockIdx.x;
    const int xcd = orig & 7, base = orig >> 3;
    const int q8 = nwg >> 3, r8 = nwg & 7;
    const int wg = (xcd < r8 ? xcd * (q8 + 1) : r8 * (q8 + 1) + (xcd - r8) * q8) + base;

    int MI = 8192 / (K << AF32);
    if (MI < 1) MI = 1;
    if (MI > (int)gridDim.y) MI = gridDim.y;
    const int slabSz = gridDim.x * MI;
    const int fullSlabs = gridDim.y / MI;
    const int fullRegion = fullSlabs * slabSz;
    int m0, n0;
    if (wg < fullRegion) {
        const int mb = wg / slabSz, rem = wg % slabSz;
        m0 = (mb * MI + rem % MI) * 128;
        n0 = (rem / MI) * 128;
    } else {
        const int rem = wg - fullRegion;
        const int TM = gridDim.y - fullSlabs * MI;
        m0 = (fullSlabs * MI + rem % TM) * 128;
        n0 = (rem / TM) * 128;
    }

    const int r = tid >> 2;
    const int ck = (tid & 3) * 8;

    const unsigned short* Wp = W + (long long)n0 * K;

    f32x4 acc[4][4] = {};
    int cur = 0;

    if constexpr (!AF32) {
        const unsigned short* Ab = (const unsigned short*)A;
        auto issue = [&](int k0, int buf) {
            const unsigned short* ga0 = Ab + (long long)(m0 + r) * K + k0 + ck;
            const unsigned short* ga1 = Ab + (long long)(m0 + r + 64) * K + k0 + ck;
            const unsigned short* gb0 = Wp + (long long)r * K + k0 + ck;
            const unsigned short* gb1 = Wp + (long long)(r + 64) * K + k0 + ck;
            char* lA = (char*)&As[buf][0][0] + wave * 1024;
            char* lB = (char*)&Bs[buf][0][0] + wave * 1024;
            GLD16(ga0, lA);
            GLD16(ga1, lA + 4096);
            GLD16(gb0, lB);
            GLD16(gb1, lB + 4096);
        };
        issue(0, 0);
        for (int k0 = 0; k0 < K; k0 += 32, cur ^= 1) {
            __syncthreads();
            if (k0 + 32 < K) issue(k0 + 32, cur ^ 1);
            const int lr = lane & 15, lk = (lane >> 4) * 8;
            bf16x8 af[4], bfr[4];
#pragma unroll
            for (int i = 0; i < 4; ++i) {
                af[i]  = *reinterpret_cast<const bf16x8*>(&As[cur][wm * 64 + i * 16 + lr][lk]);
                bfr[i] = *reinterpret_cast<const bf16x8*>(&Bs[cur][wn * 64 + i * 16 + lr][lk]);
            }
#pragma unroll
            for (int i = 0; i < 4; ++i)
#pragma unroll
                for (int j = 0; j < 4; ++j)
                    acc[i][j] = __builtin_amdgcn_mfma_f32_16x16x32_bf16(
                        af[i], bfr[j], acc[i][j], 0, 0, 0);
        }
    } else {
        const float* Af = (const float*)A;
        int4 ra0, ra1, rb0, rb1;
        ra0 = ldA8f(Af, (long long)(m0 + r) * K + ck);
        ra1 = ldA8f(Af, (long long)(m0 + r + 64) * K + ck);
        rb0 = *reinterpret_cast<const int4*>(Wp + (long long)r * K + ck);
        rb1 = *reinterpret_cast<const int4*>(Wp + (long long)(r + 64) * K + ck);
        for (int k0 = 0; k0 < K; k0 += 32, cur ^= 1) {
            *reinterpret_cast<int4*>(&As[cur][r][ck]) = ra0;
            *reinterpret_cast<int4*>(&As[cur][r + 64][ck]) = ra1;
            *reinterpret_cast<int4*>(&Bs[cur][r][ck]) = rb0;
            *reinterpret_cast<int4*>(&Bs[cur][r + 64][ck]) = rb1;
            __syncthreads();
            if (k0 + 32 < K) {
                const int kn = k0 + 32 + ck;
                ra0 = ldA8f(Af, (long long)(m0 + r) * K + kn);
                ra1 = ldA8f(Af, (long long)(m0 + r + 64) * K + kn);
                rb0 = *reinterpret_cast<const int4*>(Wp + (long long)r * K + kn);
                rb1 = *reinterpret_cast<const int4*>(Wp + (long long)(r + 64) * K + kn);
            }
            const int lr = lane & 15, lk = (lane >> 4) * 8;
            bf16x8 af[4], bfr[4];
#pragma unroll
            for (int i = 0; i < 4; ++i) {
                af[i]  = *reinterpret_cast<const bf16x8*>(&As[cur][wm * 64 + i * 16 + lr][lk]);
                bfr[i] = *reinterpret_cast<const bf16x8*>(&Bs[cur][wn * 64 + i * 16 + lr][lk]);
            }
#pragma unroll
            for (int i = 0; i < 4; ++i)
#pragma unroll
                for (int j = 0; j < 4; ++j)
                    acc[i][j] = __builtin_amdgcn_mfma_f32_16x16x32_bf16(
                        af[i], bfr[j], acc[i][j], 0, 0, 0);
        }
    }

    const int lr = lane & 15, lrow4 = (lane >> 4) * 4;
#pragma unroll
    for (int j = 0; j < 4; ++j) {
        const int col = n0 + wn * 64 + j * 16 + lr;
        if (col >= Nreal) continue;
        float bsum = 0.f;
        if (bias1) bsum += bias1[col];
        if (bias2) bsum += bias2[col];
#pragma unroll
        for (int i = 0; i < 4; ++i) {
#pragma unroll
            for (int rr = 0; rr < 4; ++rr) {
                const int row = m0 + wm * 64 + i * 16 + lrow4 + rr;
                float v = acc[i][j][rr] + bsum;
                if (ACT == 1) v = fast_tanh(v);
                if (ACT == 2) v = fmaxf(v, 0.f);
                if (OUTBF)
                    ((unsigned short*)C)[(long long)row * ldc + col] = f2bf(v);
                else
                    ((float*)C)[(long long)row * ldc + col] = v;
            }
        }
    }
}

static void mgemm(hipStream_t s, int act, int outbf, int af32,
                  const void* A, const unsigned short* W,
                  const float* b1, const float* b2,
                  void* C, long long ldc, int M, int Nreal, int K)
{
    dim3 grid((Nreal + 127) / 128, M / 128), blk(256);
#define MG(a, o, f) mfma_gemm<a, o, f><<<grid, blk, 0, s>>>(A, W, b1, b2, C, ldc, Nreal, K)
    if (af32) {
        if (outbf) { if (act == 1) MG(1,1,1); else if (act == 2) MG(2,1,1); else MG(0,1,1); }
        else       { if (act == 1) MG(1,0,1); else if (act == 2) MG(2,0,1); else MG(0,0,1); }
    } else {
        if (outbf) { if (act == 1) MG(1,1,0); else if (act == 2) MG(2,1,0); else MG(0,1,0); }
        else       { if (act == 1) MG(1,0,0); else if (act == 2) MG(2,0,0); else MG(0,0,0); }
    }
#undef MG
}

// ---------------------------------------------------------------------------
// dec2: 256x256 tile, BK=64, 512 threads (8 waves 2Mx4N), 128 KB LDS dbuf,
// counted-vmcnt pipeline + T2 XOR swizzle (rule #21: linear LDS dest,
// pre-swizzled global SOURCE, same XOR on the read).
//   layout: data (row, col) lives at LDS byte row*128 + (col*2 ^ ((row&7)<<4))
//   stage:  lane l of chunk c loads global col ((l&7)^(l>>3))*8  (involution)
//   read:   element col C -> C ^ ((row&7)*8)
// ---------------------------------------------------------------------------
__global__ __launch_bounds__(512, 1) void gemm256_kernel(
    const unsigned short* __restrict__ A, const unsigned short* __restrict__ W,
    const float* __restrict__ bias, float* __restrict__ C)
{
    __shared__ __align__(16) unsigned short As[2][256][64];
    __shared__ __align__(16) unsigned short Bs[2][256][64];
    const int tid = threadIdx.x;
    const int lane = tid & 63;
    const int wave = tid >> 6;          // 0..7
    const int wm = wave >> 2, wn = wave & 3;
    const int lr = lane & 15, hi = lane >> 4;
    const int K = 2048;

    // bijective XCD swizzle + MI=2 L2-blocked walk over grid (36 x 20)
    const int nwg = gridDim.x * gridDim.y;
    const int orig = blockIdx.y * gridDim.x + blockIdx.x;
    const int xcd = orig & 7, base = orig >> 3;
    const int q8 = nwg >> 3, r8 = nwg & 7;
    const int wg = (xcd < r8 ? xcd * (q8 + 1) : r8 * (q8 + 1) + (xcd - r8) * q8) + base;
    const int MI = 2;
    const int slabSz = gridDim.x * MI;          // 72
    int m0, n0;
    {
        const int mb = wg / slabSz, rem = wg % slabSz;
        m0 = (mb * MI + rem % MI) * 256;
        n0 = (rem / MI) * 256;
    }

    // staging: chunk c (0..31) = rows 8c..8c+7; lane l writes LDS byte
    // c*1024 + l*16 linearly; pre-swizzled source col makes the layout
    // row*128 + (col*2 ^ ((row&7)<<4)).
    const int srow = lane >> 3;                       // 0..7 (= row&7)
    const int scol = ((lane & 7) ^ srow) * 8;         // pre-swizzled column
    auto stage = [&](int kt, int b) {
#pragma unroll
        for (int q = 0; q < 4; ++q) {
            const int c = wave * 4 + q;
            const unsigned short* ga = A + (long long)(m0 + 8 * c + srow) * K + kt * 64 + scol;
            GLD16(ga, (char*)&As[b][0][0] + c * 1024);
        }
#pragma unroll
        for (int q = 0; q < 4; ++q) {
            const int c = wave * 4 + q;
            const unsigned short* gw = W + (long long)(n0 + 8 * c + srow) * K + kt * 64 + scol;
            GLD16(gw, (char*)&Bs[b][0][0] + c * 1024);
        }
    };

    f32x4 acc[8][4] = {};
    const int nt = K / 64;   // 32
    const int cx = ((lr & 7) * 8);   // read-side XOR (row&7 == lr&7)
    stage(0, 0);
    stage(1, 1);

    for (int t = 0; t < nt; ++t) {
        const int b = t & 1;
        if (t + 1 < nt) asm volatile("s_waitcnt vmcnt(8)" ::: "memory");
        else            asm volatile("s_waitcnt vmcnt(0)" ::: "memory");
        __builtin_amdgcn_s_barrier();   // all waves' tile-t loads landed

        // phases 0..2: (mh,ks) = (0,0),(1,0),(0,1)
#pragma unroll
        for (int p = 0; p < 3; ++p) {
            const int mh = p & 1, ks = p >> 1;
            const int col = (ks * 32 + hi * 8) ^ cx;
            bf16x8 af[4], bfr[4];
#pragma unroll
            for (int i = 0; i < 4; ++i) {
                af[i]  = *reinterpret_cast<const bf16x8*>(
                    &As[b][wm * 128 + mh * 64 + i * 16 + lr][col]);
                bfr[i] = *reinterpret_cast<const bf16x8*>(
                    &Bs[b][wn * 64 + i * 16 + lr][col]);
            }
            __builtin_amdgcn_s_setprio(1);
#pragma unroll
            for (int i = 0; i < 4; ++i)
#pragma unroll
                for (int j = 0; j < 4; ++j)
                    acc[mh * 4 + i][j] = __builtin_amdgcn_mfma_f32_16x16x32_bf16(
                        af[i], bfr[j], acc[mh * 4 + i][j], 0, 0, 0);
            __builtin_amdgcn_s_setprio(0);
            __builtin_amdgcn_s_barrier();
        }
        // phase 3: (mh,ks) = (1,1); read; lgkmcnt(0)+sched_barrier pins the
        // ds_reads BEFORE the barrier (rule #18); then barrier -> buffer b is
        // free -> stage tile t+2 into it -> MFMA on the register values.
        {
            const int col = (32 + hi * 8) ^ cx;
            bf16x8 af[4], bfr[4];
#pragma unroll
            for (int i = 0; i < 4; ++i) {
                af[i]  = *reinterpret_cast<const bf16x8*>(
                    &As[b][wm * 128 + 64 + i * 16 + lr][col]);
                bfr[i] = *reinterpret_cast<const bf16x8*>(
                    &Bs[b][wn * 64 + i * 16 + lr][col]);
            }
            asm volatile("s_waitcnt lgkmcnt(0)" ::: "memory");
            __builtin_amdgcn_sched_barrier(0);
            __builtin_amdgcn_s_barrier();   // all waves done reading buf b
            if (t + 2 < nt) stage(t + 2, b);
            __builtin_amdgcn_s_setprio(1);
#pragma unroll
            for (int i = 0; i < 4; ++i)
#pragma unroll
                for (int j = 0; j < 4; ++j)
                    acc[4 + i][j] = __builtin_amdgcn_mfma_f32_16x16x32_bf16(
                        af[i], bfr[j], acc[4 + i][j], 0, 0, 0);
            __builtin_amdgcn_s_setprio(0);
        }
    }

    // epilogue: row = m0 + wm*128 + i8*16 + hi*4 + rr ; col = n0 + wn*64 + j*16 + lr
#pragma unroll
    for (int j = 0; j < 4; ++j) {
        const int col = n0 + wn * 64 + j * 16 + lr;
        if (col >= V_) continue;
        const float bsum = bias[col];
#pragma unroll
        for (int i8 = 0; i8 < 8; ++i8) {
#pragma unroll
            for (int rr = 0; rr < 4; ++rr) {
                const int row = m0 + wm * 128 + i8 * 16 + hi * 4 + rr;
                C[(long long)row * V_ + col] = acc[i8][j][rr] + bsum;
            }
        }
    }
}

// ---------------------------------------------------------------------------
// MEGA kernel (unchanged).
// ---------------------------------------------------------------------------
#define LSTM_ISSUE(b_, dst_) do {                                              \
    const unsigned short* pa_ = (((b_) >> 2) ? q20 : q10) + ((b_) & 3) * 128;  \
    const unsigned short* pb_ = (((b_) >> 2) ? q21 : q11) + ((b_) & 3) * 128;  \
    asm volatile(                                                              \
        "global_load_dwordx4 %0, %[pa], off sc0 sc1\n\t"                       \
        "global_load_dwordx4 %1, %[pa], off offset:64 sc0 sc1\n\t"             \
        "global_load_dwordx4 %2, %[pa], off offset:128 sc0 sc1\n\t"            \
        "global_load_dwordx4 %3, %[pa], off offset:192 sc0 sc1\n\t"            \
        "global_load_dwordx4 %4, %[pb], off sc0 sc1\n\t"                       \
        "global_load_dwordx4 %5, %[pb], off offset:64 sc0 sc1\n\t"             \
        "global_load_dwordx4 %6, %[pb], off offset:128 sc0 sc1\n\t"            \
        "global_load_dwordx4 %7, %[pb], off offset:192 sc0 sc1"                \
        : "=&v"((dst_)[0]), "=&v"((dst_)[1]), "=&v"((dst_)[2]), "=&v"((dst_)[3]), \
          "=&v"((dst_)[4]), "=&v"((dst_)[5]), "=&v"((dst_)[6]), "=&v"((dst_)[7])  \
        : [pa] "v"(pa_), [pb] "v"(pb_)                                         \
        : "memory");                                                           \
} while (0)

__global__ __launch_bounds__(256, 1) void mega_kernel(
    const unsigned short* __restrict__ emb_bf,
    const unsigned short* __restrict__ Wih0p, const unsigned short* __restrict__ Whh0p,
    const unsigned short* __restrict__ Wih1p, const unsigned short* __restrict__ Whh1p,
    const float* __restrict__ bp0, const float* __restrict__ bp1,
    const float* __restrict__ c0,
    unsigned short* __restrict__ hbuf,
    float* __restrict__ st_h, float* __restrict__ st_c,
    unsigned short* __restrict__ h_top,
    int* flags,
    const float* __restrict__ question, const float* __restrict__ history,
    const float* __restrict__ image,
    const unsigned short* __restrict__ Wq_bf, const unsigned short* __restrict__ Wh_bf,
    const unsigned short* __restrict__ Wi_bf,
    const float* __restrict__ bq, const float* __restrict__ bhb,
    const float* __restrict__ bi,
    unsigned short* __restrict__ q_emb, unsigned short* __restrict__ h_emb,
    unsigned short* __restrict__ i_emb)
{
    __shared__ __align__(16) char smem[131072];
    const int gid = blockIdx.x;
    const int tid = threadIdx.x;

    if (gid >= MEGA_LSTM_) {
        int g = gid - MEGA_LSTM_;
        const float* A; const unsigned short* W; const float* bias;
        unsigned short* Cc;
        if (g < MEGA_CTXQ_)       { A = question; W = Wq_bf; bias = bq;  Cc = q_emb; }
        else if (g < MEGA_CTXQ_ + MEGA_CTXH_) {
            g -= MEGA_CTXQ_;        A = history;  W = Wh_bf; bias = bhb; Cc = h_emb; }
        else { g -= MEGA_CTXQ_ + MEGA_CTXH_; A = image; W = Wi_bf; bias = bi; Cc = i_emb; }
        const int m0 = (g >> 2) * 128, n0 = (g & 3) * 128;
        const int K = 1024;

        unsigned short (*As)[128][32] = (unsigned short (*)[128][32])smem;
        unsigned short (*Bs)[128][32] = (unsigned short (*)[128][32])(smem + 16384);
        const int lane = tid & 63;
        const int wave = tid >> 6;
        const int wm = wave >> 1, wn = wave & 1;
        const int r = tid >> 2;
        const int ck = (tid & 3) * 8;
        const unsigned short* Wp = W + (long long)n0 * K;

        f32x4 acc[4][4] = {};
        int4 ra0, ra1, rb0, rb1;
        ra0 = ldA8f(A, (long long)(m0 + r) * K + ck);
        ra1 = ldA8f(A, (long long)(m0 + r + 64) * K + ck);
        rb0 = *reinterpret_cast<const int4*>(Wp + (long long)r * K + ck);
        rb1 = *reinterpret_cast<const int4*>(Wp + (long long)(r + 64) * K + ck);
        int cur = 0;
        for (int k0 = 0; k0 < K; k0 += 32, cur ^= 1) {
            *reinterpret_cast<int4*>(&As[cur][r][ck]) = ra0;
            *reinterpret_cast<int4*>(&As[cur][r + 64][ck]) = ra1;
            *reinterpret_cast<int4*>(&Bs[cur][r][ck]) = rb0;
            *reinterpret_cast<int4*>(&Bs[cur][r + 64][ck]) = rb1;
            __syncthreads();
            if (k0 + 32 < K) {
                const int kn = k0 + 32 + ck;
                ra0 = ldA8f(A, (long long)(m0 + r) * K + kn);
                ra1 = ldA8f(A, (long long)(m0 + r + 64) * K + kn);
                rb0 = *reinterpret_cast<const int4*>(Wp + (long long)r * K + kn);
                rb1 = *reinterpret_cast<const int4*>(Wp + (long long)(r + 64) * K + kn);
            }
            const int lr = lane & 15, lk = (lane >> 4) * 8;
            bf16x8 af[4], bfr[4];
#pragma unroll
            for (int i = 0; i < 4; ++i) {
                af[i]  = *reinterpret_cast<const bf16x8*>(&As[cur][wm * 64 + i * 16 + lr][lk]);
                bfr[i] = *reinterpret_cast<const bf16x8*>(&Bs[cur][wn * 64 + i * 16 + lr][lk]);
            }
#pragma unroll
            for (int i = 0; i < 4; ++i)
#pragma unroll
                for (int j = 0; j < 4; ++j)
                    acc[i][j] = __builtin_amdgcn_mfma_f32_16x16x32_bf16(
                        af[i], bfr[j], acc[i][j], 0, 0, 0);
        }
        const int lr = lane & 15, lrow4 = (lane >> 4) * 4;
#pragma unroll
        for (int j = 0; j < 4; ++j) {
            const int col = n0 + wn * 64 + j * 16 + lr;
            const float bsum = bias[col];
#pragma unroll
            for (int i = 0; i < 4; ++i)
#pragma unroll
                for (int rr = 0; rr < 4; ++rr) {
                    const int row = m0 + wm * 64 + i * 16 + lrow4 + rr;
                    Cc[(long long)row * 512 + col] = f2bf(acc[i][j][rr] + bsum);
                }
        }
        return;
    }

    const int grp = gid >> 6;
    const int id  = gid & 63;
    const int mt = id >> 5, nt = id & 31;
    const int m0 = mt * 128, n0 = nt * 64;
    const int lane = tid & 63;
    const int w = tid >> 6;
    const int lr = lane & 15;
    const int hi = lane >> 4;
    const int hi4 = hi * 4;

    const unsigned short* W1g = (grp ? Wih1p : Wih0p) + (long long)n0 * H_;
    const unsigned short* W2g = (grp ? Whh1p : Whh0p) + (long long)n0 * H_;

#pragma unroll
    for (int it = 0; it < 16; ++it) {
        const int e = (tid + it * 256) * 8;
        const int row = e >> 9, col = e & 511;
        const int bir = (col * 2) ^ ((row & 7) << 4);
        char* dst = smem + row * 1024 + bir;
        *reinterpret_cast<int4*>(dst) =
            *reinterpret_cast<const int4*>(W1g + (long long)row * H_ + col);
        *reinterpret_cast<int4*>(dst + 65536) =
            *reinterpret_cast<const int4*>(W2g + (long long)row * H_ + col);
    }
    __syncthreads();

    const int h = nt * 16 + lr;
    const float* bp = grp ? bp1 : bp0;
    float bg[4];
#pragma unroll
    for (int g = 0; g < 4; ++g) bg[g] = bp[n0 + g * 16 + lr];

    const int ar0 = m0 + w * 32 + lr;
    const int ar1 = ar0 + 16;

    float cregA[4], cregB[4], hn0[4], hn1[4];
#pragma unroll
    for (int rr = 0; rr < 4; ++rr) {
        cregA[rr] = c0[(long long)grp * BH_ + (long long)(m0 + w * 32 + hi4 + rr) * H_ + h];
        cregB[rr] = c0[(long long)grp * BH_ + (long long)(m0 + w * 32 + 16 + hi4 + rr) * H_ + h];
    }

    int bbase[4];
#pragma unroll
    for (int j = 0; j < 4; ++j)
        bbase[j] = (j * 16 + lr) * 1024 + ((hi * 16) ^ ((lr & 3) << 4));
    const int xk6 = ((lr >> 2) & 1) << 6;

    int* myFlag = flags + (mt * 64 + grp * 32 + nt) * 16;
    const long long sEmb = (long long)T_ * H_;

    for (int s = 0; s <= T_; ++s) {
        const bool active = (grp == 0) ? (s < T_) : (s >= 1);
        const int t = grp ? (s - 1) : s;
        if (active) {
            const unsigned short *A1, *A2;
            long long sA1;
            unsigned short* hout;
            if (grp == 0) {
                A1 = emb_bf + (long long)t * H_; sA1 = sEmb;
                A2 = hbuf + (long long)(s % 3) * BH_;
                hout = hbuf + (long long)((s + 1) % 3) * BH_;
            } else {
                A1 = hbuf + (long long)(s % 3) * BH_; sA1 = H_;
                A2 = hbuf + (long long)(3 + (s & 1)) * BH_;
                hout = hbuf + (long long)(3 + ((s + 1) & 1)) * BH_;
            }
            const unsigned short* q10 = A1 + (long long)ar0 * sA1 + hi * 8;
            const unsigned short* q11 = A1 + (long long)ar1 * sA1 + hi * 8;
            const unsigned short* q20 = A2 + (long long)ar0 * H_ + hi * 8;
            const unsigned short* q21 = A2 + (long long)ar1 * H_ + hi * 8;

            int4 buf[3][8];
            LSTM_ISSUE(0, buf[0]);
            LSTM_ISSUE(1, buf[1]);
            LSTM_ISSUE(2, buf[2]);

            f32x4 accA[4] = {}, accB[4] = {};
#pragma unroll
            for (int b = 0; b < 8; ++b) {
                if (b < 6)      asm volatile("s_waitcnt vmcnt(16)" ::: "memory");
                else if (b == 6) asm volatile("s_waitcnt vmcnt(8)" ::: "memory");
                else             asm volatile("s_waitcnt vmcnt(0)" ::: "memory");
                __builtin_amdgcn_sched_barrier(0);
#pragma unroll
                for (int i = 0; i < 4; ++i) {
                    const int it = b * 4 + i;
                    const int kk = it & 15, p = it >> 4;
                    const bf16x8 a0 = *reinterpret_cast<const bf16x8*>(&buf[b % 3][i]);
                    const bf16x8 a1 = *reinterpret_cast<const bf16x8*>(&buf[b % 3][4 + i]);
                    const int kb = ((kk << 6) ^ xk6) + (p << 16);
#pragma unroll
                    for (int j = 0; j < 4; ++j) {
                        const bf16x8 bfv = *reinterpret_cast<const bf16x8*>(
                            smem + bbase[j] + kb);
                        accA[j] = __builtin_amdgcn_mfma_f32_16x16x32_bf16(a0, bfv, accA[j], 0, 0, 0);
                        accB[j] = __builtin_amdgcn_mfma_f32_16x16x32_bf16(a1, bfv, accB[j], 0, 0, 0);
                    }
                }
                if (b + 3 < 8) LSTM_ISSUE(b + 3, buf[b % 3]);
            }

#pragma unroll
            for (int rr = 0; rr < 4; ++rr) {
                {
                    const int b = m0 + w * 32 + hi4 + rr;
                    const float i_ = fast_sigmoid(accA[0][rr] + bg[0]);
                    const float f_ = fast_sigmoid(accA[1][rr] + bg[1]);
                    const float g_ = fast_tanh(accA[2][rr] + bg[2]);
                    const float o_ = fast_sigmoid(accA[3][rr] + bg[3]);
                    const float cn = f_ * cregA[rr] + i_ * g_;
                    const float hn = o_ * fast_tanh(cn);
                    cregA[rr] = cn; hn0[rr] = hn;
                    st16_sc(&hout[(long long)b * H_ + h], f2bf(hn));
                }
                {
                    const int b = m0 + w * 32 + 16 + hi4 + rr;
                    const float i_ = fast_sigmoid(accB[0][rr] + bg[0]);
                    const float f_ = fast_sigmoid(accB[1][rr] + bg[1]);
                    const float g_ = fast_tanh(accB[2][rr] + bg[2]);
                    const float o_ = fast_sigmoid(accB[3][rr] + bg[3]);
                    const float cn = f_ * cregB[rr] + i_ * g_;
                    const float hn = o_ * fast_tanh(cn);
                    cregB[rr] = cn; hn1[rr] = hn;
                    st16_sc(&hout[(long long)b * H_ + h], f2bf(hn));
                }
            }
            if (s == T_) {
#pragma unroll
                for (int rr = 0; rr < 4; ++rr) {
                    const int b0r = m0 + w * 32 + hi4 + rr;
                    const int b1r = b0r + 16;
                    h_top[((long long)b0r * T_ + t) * H_ + h] = f2bf(hn0[rr]);
                    h_top[((long long)b1r * T_ + t) * H_ + h] = f2bf(hn1[rr]);
                    st_h[(long long)grp * BH_ + (long long)b0r * H_ + h] = hn0[rr];
                    st_h[(long long)grp * BH_ + (long long)b1r * H_ + h] = hn1[rr];
                    st_c[(long long)grp * BH_ + (long long)b0r * H_ + h] = cregA[rr];
                    st_c[(long long)grp * BH_ + (long long)b1r * H_ + h] = cregB[rr];
                }
            }
        }
        if (s < T_) {
            __syncthreads();
            if (tid == 0) {
                int v = s + 1;
                asm volatile("global_store_dword %0, %1, off sc0 sc1"
                             :: "v"(myFlag), "v"(v) : "memory");
            }
            if (active) {
#pragma unroll
                for (int rr = 0; rr < 4; ++rr) {
                    const int b0r = m0 + w * 32 + hi4 + rr;
                    const int b1r = b0r + 16;
                    if (grp == 1) {
                        h_top[((long long)b0r * T_ + t) * H_ + h] = f2bf(hn0[rr]);
                        h_top[((long long)b1r * T_ + t) * H_ + h] = f2bf(hn1[rr]);
                    }
                    if (t == T_ - 1) {
                        st_h[(long long)grp * BH_ + (long long)b0r * H_ + h] = hn0[rr];
                        st_h[(long long)grp * BH_ + (long long)b1r * H_ + h] = hn1[rr];
                        st_c[(long long)grp * BH_ + (long long)b0r * H_ + h] = cregA[rr];
                        st_c[(long long)grp * BH_ + (long long)b1r * H_ + h] = cregB[rr];
                    }
                }
            }
            if (tid < 64) {
                const int thr = (grp == 0 && tid >= 32) ? s : s + 1;
                const int* fp = flags + (mt * 64 + tid) * 16;
                while (ld32_sc(fp) < thr) __builtin_amdgcn_s_sleep(2);
            }
            __syncthreads();
        }
    }
}

// ---------------------------------------------------------------------------
// Triple attention (unchanged).
// ---------------------------------------------------------------------------
__global__ __launch_bounds__(256) void attend3_kernel(
    const unsigned short* __restrict__ q_emb, const unsigned short* __restrict__ h_emb,
    const unsigned short* __restrict__ i_emb,
    const float* __restrict__ proj3,
    const float* __restrict__ waq, const float* __restrict__ baq, const float* __restrict__ bansq,
    const float* __restrict__ wah, const float* __restrict__ bah, const float* __restrict__ bansh,
    const float* __restrict__ wai, const float* __restrict__ bai, const float* __restrict__ bansi,
    const unsigned short* __restrict__ h_top,
    unsigned short* __restrict__ fcat, unsigned short* __restrict__ fusion)
{
    __shared__ float p_lds[512];
    __shared__ float wa_lds[512];
    __shared__ float lg[96];
    const int bt0 = blockIdx.x;
    const int bt = (bt0 & 7) * (BT_ / 8) + (bt0 >> 3);
    const int c = blockIdx.y;
    const int b = bt / T_;
    const int tid = threadIdx.x;
    const int wid = tid >> 6, lane = tid & 63;

    if (c == 0 && tid < 64)
        *reinterpret_cast<u16x8*>(&fusion[(long long)bt * 1024 + tid * 8]) =
            *reinterpret_cast<const u16x8*>(&h_top[(long long)bt * 512 + tid * 8]);

    const unsigned short* ctx = c == 0 ? q_emb : c == 1 ? h_emb : i_emb;
    const int Lx = c == 0 ? LQ_ : c == 1 ? LH_ : LI_;
    const float* wa = c == 0 ? waq : c == 1 ? wah : wai;
    const float bav = (c == 0 ? baq : c == 1 ? bah : bai)[0];
    const float* bans = c == 0 ? bansq : c == 1 ? bansh : bansi;

    p_lds[tid]       = proj3[(long long)bt * 1536 + c * 512 + tid] + bans[tid];
    p_lds[tid + 256] = proj3[(long long)bt * 1536 + c * 512 + tid + 256] + bans[tid + 256];
    wa_lds[tid] = wa[tid];
    wa_lds[tid + 256] = wa[tid + 256];
    __syncthreads();

    for (int l = wid; l < Lx; l += 4) {
        const unsigned short* crow = ctx + ((long long)b * Lx + l) * H_;
        float acc = 0.f;
#pragma unroll
        for (int j = 0; j < 8; ++j) {
            const int hp = lane + 64 * j;
            acc += wa_lds[hp] * fast_tanh(bf2f(crow[hp]) + p_lds[hp]);
        }
        for (int o = 32; o > 0; o >>= 1) acc += __shfl_down(acc, o);
        if (lane == 0) lg[l] = acc + bav;
    }
    __syncthreads();
    if (tid == 0) {
        float m = -1e30f;
        for (int l = 0; l < Lx; ++l) m = fmaxf(m, lg[l]);
        float ssum = 0.f;
        for (int l = 0; l < Lx; ++l) { const float e = __expf(lg[l] - m); lg[l] = e; ssum += e; }
        const float inv = __builtin_amdgcn_rcpf(ssum);
        for (int l = 0; l < Lx; ++l) lg[l] *= inv;
    }
    __syncthreads();
    for (int hp = tid; hp < H_; hp += 256) {
        float acc = 0.f;
        for (int l = 0; l < Lx; ++l)
            acc += lg[l] * bf2f(ctx[((long long)b * Lx + l) * H_ + hp]);
        fcat[(long long)bt * 1536 + c * 512 + hp] = f2bf(acc);
    }
}

// In-place log_softmax(BETA * x) per row of V_; row cached in registers.
__global__ __launch_bounds__(256) void log_softmax_kernel(float* __restrict__ out)
{
    __shared__ float red[4];
    __shared__ float bc;
    const long long base = (long long)blockIdx.x * V_;
    const int tid = threadIdx.x, lane = tid & 63, wid = tid >> 6;

    float r[36];
    float m = -1e30f;
#pragma unroll
    for (int i = 0; i < 36; ++i) {
        const int v = tid + i * 256;
        r[i] = (v < V_) ? BETA_ * out[base + v] : -1e30f;
        m = fmaxf(m, r[i]);
    }
    for (int o = 32; o > 0; o >>= 1) m = fmaxf(m, __shfl_down(m, o));
    if (lane == 0) red[wid] = m;
    __syncthreads();
    if (tid == 0)
        bc = fmaxf(fmaxf(red[0], red[1]), fmaxf(red[2], red[3]));
    __syncthreads();
    m = bc;

    float s = 0.f;
#pragma unroll
    for (int i = 0; i < 36; ++i) s += __expf(r[i] - m);
    for (int o = 32; o > 0; o >>= 1) s += __shfl_down(s, o);
    if (lane == 0) red[wid] = s;
    __syncthreads();
    if (tid == 0) bc = m + logf(red[0] + red[1] + red[2] + red[3]);
    __syncthreads();
    const float ls = bc;
#pragma unroll
    for (int i = 0; i < 36; ++i) {
        const int v = tid + i * 256;
        if (v < V_) out[base + v] = r[i] - ls;
    }
}

// ---------------------------------------------------------------------------
extern "C" void kernel_launch(void* const* d_in, const int* in_sizes, int n_in,
                              void* d_out_, int out_size, void* d_ws, size_t ws_size,
                              hipStream_t stream)
{
    const float* emb      = (const float*)d_in[0];
    const float* question = (const float*)d_in[1];
    const float* history  = (const float*)d_in[2];
    const float* image    = (const float*)d_in[3];
    const float* h0       = (const float*)d_in[4];
    const float* c0       = (const float*)d_in[5];
    const float* Wih      = (const float*)d_in[6];
    const float* Whh      = (const float*)d_in[7];
    const float* bih      = (const float*)d_in[8];
    const float* bhh      = (const float*)d_in[9];
    const float* Wq    = (const float*)d_in[10]; const float* bq    = (const float*)d_in[11];
    const float* Wansq = (const float*)d_in[12]; const float* bansq = (const float*)d_in[13];
    const float* waq   = (const float*)d_in[14]; const float* baq   = (const float*)d_in[15];
    const float* Wh    = (const float*)d_in[16]; const float* bh    = (const float*)d_in[17];
    const float* Wansh = (const float*)d_in[18]; const float* bansh = (const float*)d_in[19];
    const float* wah   = (const float*)d_in[20]; const float* bah   = (const float*)d_in[21];
    const float* Wi    = (const float*)d_in[22]; const float* bi    = (const float*)d_in[23];
    const float* Wansi = (const float*)d_in[24]; const float* bansi = (const float*)d_in[25];
    const float* wai   = (const float*)d_in[26]; const float* bai   = (const float*)d_in[27];
    const float* Wcat  = (const float*)d_in[28]; const float* bcat  = (const float*)d_in[29];
    const float* Wd1   = (const float*)d_in[30]; const float* bd1   = (const float*)d_in[31];
    const float* Wd2   = (const float*)d_in[32]; const float* bd2   = (const float*)d_in[33];

    float* out = (float*)d_out_;

    // ---- workspace layout ----
    int*   flags = (int*)d_ws;
    float* st_h = (float*)((char*)d_ws + 8192);
    float* st_c = st_h + 2LL * BH_;
    float* bp0  = st_c + 2LL * BH_;
    float* bp1  = bp0 + 2048;
    unsigned short* hbuf   = (unsigned short*)(bp1 + 2048);
    unsigned short* Wih0p  = hbuf + 5LL * BH_;
    unsigned short* Whh0p  = Wih0p + 2048LL * H_;
    unsigned short* Wih1p  = Whh0p + 2048LL * H_;
    unsigned short* Whh1p  = Wih1p + 2048LL * H_;
    unsigned short* emb_bf = Whh1p + 2048LL * H_;
    unsigned short* h_top_bf = emb_bf + (long long)BT_ * H_;
    unsigned short* q_emb_bf = h_top_bf + (long long)BT_ * H_;
    unsigned short* h_emb_bf = q_emb_bf + (long long)B_ * LQ_ * H_;
    unsigned short* i_emb_bf = h_emb_bf + (long long)B_ * LH_ * H_;
    unsigned short* dec1_bf  = i_emb_bf + (long long)B_ * LI_ * H_;
    unsigned short* Wd2p_bf  = dec1_bf + (long long)BT_ * 4 * H_;   // NPAD_*2048

    // ---- scratch inside d_out ----
    unsigned short* Wq_bf    = (unsigned short*)out;
    unsigned short* Wh_bf    = Wq_bf + 524288;
    unsigned short* Wi_bf    = Wh_bf + 524288;
    unsigned short* Wansq_bf = Wi_bf + 524288;
    unsigned short* Wansh_bf = Wansq_bf + 262144;
    unsigned short* Wansi_bf = Wansh_bf + 262144;
    unsigned short* Wcat_bf  = Wansi_bf + 262144;
    unsigned short* Wd1_bf   = Wcat_bf + 786432;
    float* proj3 = (float*)(Wd1_bf + 2097152);
    unsigned short* fcat_bf   = (unsigned short*)(proj3 + (long long)BT_ * 1536);
    unsigned short* fusion_bf = fcat_bf + (long long)BT_ * 1536;

    // 1) ALL prep in ONE launch
    {
        PrepArgs a;
        a.wsrc[0] = Wq;    a.wdst[0] = Wq_bf;
        a.wsrc[1] = Wh;    a.wdst[1] = Wh_bf;
        a.wsrc[2] = Wi;    a.wdst[2] = Wi_bf;
        a.wsrc[3] = Wansq; a.wdst[3] = Wansq_bf;
        a.wsrc[4] = Wansh; a.wdst[4] = Wansh_bf;
        a.wsrc[5] = Wansi; a.wdst[5] = Wansi_bf;
        a.wsrc[6] = Wcat;  a.wdst[6] = Wcat_bf;
        a.wsrc[7] = Wd1;   a.wdst[7] = Wd1_bf;
        a.Wd2 = Wd2; a.Wd2p = Wd2p_bf;
        a.emb = emb; a.emb_bf = emb_bf;
        a.psrc[0] = Wih;               a.pdst[0] = Wih0p;
        a.psrc[1] = Whh;               a.pdst[1] = Whh0p;
        a.psrc[2] = Wih + 2048LL * H_; a.pdst[2] = Wih1p;
        a.psrc[3] = Whh + 2048LL * H_; a.pdst[3] = Whh1p;
        a.h0 = h0; a.hbuf = hbuf;
        a.bih = bih; a.bhh = bhh; a.bp0 = bp0; a.bp1 = bp1;
        prep_kernel<<<dim3(PREP_GRID_), dim3(256), 0, stream>>>(a);
    }
    hipMemsetAsync(flags, 0, 8192, stream);

    // 2) MEGA: persistent LSTM (blocks 0-127) || ctx projections
    mega_kernel<<<dim3(MEGA_GRID_), dim3(256), 0, stream>>>(
        emb_bf, Wih0p, Whh0p, Wih1p, Whh1p, bp0, bp1, c0,
        hbuf, st_h, st_c, h_top_bf, flags,
        question, history, image, Wq_bf, Wh_bf, Wi_bf, bq, bh, bi,
        q_emb_bf, h_emb_bf, i_emb_bf);

    // 3) attention: one proj GEMM (N=1536) + attend3 grid (BT,3)
    mgemm(stream, 0, 0, 0, h_top_bf, Wansq_bf, nullptr, nullptr, proj3, 1536, BT_, 1536, H_);
    attend3_kernel<<<dim3(BT_, 3), dim3(256), 0, stream>>>(
        q_emb_bf, h_emb_bf, i_emb_bf, proj3,
        waq, baq, bansq, wah, bah, bansh, wai, bai, bansi,
        h_top_bf, fcat_bf, fusion_bf);

    // 4) fusion right half = tanh(fcat @ Wcat^T + bcat)
    mgemm(stream, 1, 1, 0, fcat_bf, Wcat_bf, bcat, nullptr, fusion_bf + H_, 2 * H_, BT_, H_, 3 * H_);

    // 5) decoder: dec1 (128-tile) then dec2 (swizzled 256-tile)
    mgemm(stream, 2, 1, 0, fusion_bf, Wd1_bf, bd1, nullptr, dec1_bf, 4 * H_, BT_, 4 * H_, 2 * H_);
    gemm256_kernel<<<dim3(NPAD_ / 256, BT_ / 256), dim3(512), 0, stream>>>(
        dec1_bf, Wd2p_bf, bd2, out);

    // 6) log_softmax
    log_softmax_kernel<<<dim3(BT_), dim3(256), 0, stream>>>(out);

    // 7) tail: hT, cT
    hipMemcpyAsync(out + (long long)BT_ * V_, st_h,
                   4LL * BH_ * sizeof(float), hipMemcpyDeviceToDevice, stream);
}